// Round 1
// baseline (80005.542 us; speedup 1.0000x reference)
//
#include <hip/hip_runtime.h>
#include <math.h>

// Problem constants
// B=256, T_ENC=200, D=256, T_MEL=1000, NMEL=80, R=5, IN_R=400, Td=200
#define ALIGN_OFF 20480000   // 256*200*400

__device__ __forceinline__ float sigmoidf_(float x){ return 1.0f/(1.0f+expf(-x)); }

// ---------------------------------------------------------------------------
// Generic 64x64-tile fp32 GEMM: C = act(A @ W^T + bias)
// AMODE: 0 = plain A[m*lda+k]
//        1 = concat(A1 [Ka cols], A2 [Kb cols])
//        2 = "prev" virtual A for prenet1: row m -> t=m>>8, b=m&255;
//            t==0 -> zeros, else inputs[b*80000 + (t-1)*400 + k]
// EPI:   0 = plain store, 1 = relu, 2 = mel-layout store out[b*80000+t*400+n]
// ---------------------------------------------------------------------------
template<int AMODE, int EPI>
__global__ __launch_bounds__(256)
void gemm_kernel(const float* __restrict__ A1, int lda1, int Ka,
                 const float* __restrict__ A2, int lda2, int Kb,
                 const float* __restrict__ W, int ldw,
                 const float* __restrict__ bias,
                 float* __restrict__ C, int ldc, int M, int N)
{
    __shared__ float As[64][17];
    __shared__ float Ws[64][17];
    const int m0 = blockIdx.x * 64, n0 = blockIdx.y * 64;
    const int tid = threadIdx.x, tx = tid & 15, ty = tid >> 4;
    float acc[4][4] = {};
    const int K = Ka + Kb;
    for (int k0 = 0; k0 < K; k0 += 16) {
        #pragma unroll
        for (int i = 0; i < 4; ++i) {
            int e = tid + i * 256; int r = e >> 4, kk = e & 15;
            int m = m0 + r, k = k0 + kk;
            float v;
            if (AMODE == 2) {
                int t = m >> 8, b = m & 255;
                v = (t == 0) ? 0.0f : A1[b * 80000 + (t - 1) * 400 + k];
            } else if (AMODE == 1) {
                v = (k < Ka) ? A1[m * lda1 + k] : A2[m * lda2 + (k - Ka)];
            } else {
                v = A1[m * lda1 + k];
            }
            As[r][kk] = v;
        }
        #pragma unroll
        for (int i = 0; i < 4; ++i) {
            int e = tid + i * 256; int r = e >> 4, kk = e & 15;
            int n = n0 + r, k = k0 + kk;
            Ws[r][kk] = (n < N) ? W[n * ldw + k] : 0.0f;
        }
        __syncthreads();
        #pragma unroll
        for (int kk = 0; kk < 16; ++kk) {
            float a[4], b[4];
            #pragma unroll
            for (int i = 0; i < 4; ++i) a[i] = As[ty + 16 * i][kk];
            #pragma unroll
            for (int j = 0; j < 4; ++j) b[j] = Ws[tx + 16 * j][kk];
            #pragma unroll
            for (int i = 0; i < 4; ++i)
                #pragma unroll
                for (int j = 0; j < 4; ++j)
                    acc[i][j] += a[i] * b[j];
        }
        __syncthreads();
    }
    #pragma unroll
    for (int i = 0; i < 4; ++i) {
        int row = m0 + ty + 16 * i;
        #pragma unroll
        for (int j = 0; j < 4; ++j) {
            int col = n0 + tx + 16 * j;
            if (col >= N) continue;
            float v = acc[i][j] + (bias ? bias[col] : 0.0f);
            if (EPI == 1) v = fmaxf(v, 0.0f);
            if (EPI == 2) {
                int t = row >> 8, b = row & 255;
                C[(size_t)b * 80000 + t * 400 + col] = v;
            } else {
                C[(size_t)row * ldc + col] = v;
            }
        }
    }
}

// ---------------------------------------------------------------------------
// Fused GRU cell: h' = GRU(concat(xa,xb), h); optionally sum_out = h' + add_in
// Grid: (B/64, 256/64) = (4,4); block 256 threads.
// ---------------------------------------------------------------------------
__global__ __launch_bounds__(256)
void gru_kernel(const float* __restrict__ xa, int lda_a, int Ka,
                const float* __restrict__ xb, int lda_b, int Kb,
                const float* __restrict__ h,
                const float* __restrict__ Wih, int ldw_i,
                const float* __restrict__ bih,
                const float* __restrict__ Whh,
                const float* __restrict__ bhh,
                float* __restrict__ h_out,
                const float* __restrict__ add_in,
                float* __restrict__ sum_out)
{
    __shared__ float As[64][17];
    __shared__ float Ws[3][64][17];
    const int m0 = blockIdx.x * 64, n0 = blockIdx.y * 64;
    const int tid = threadIdx.x, tx = tid & 15, ty = tid >> 4;
    float acci[3][4][4] = {};
    float acch[3][4][4] = {};
    const int K1 = Ka + Kb;
    // sweep 1: gi = x @ Wih^T
    for (int k0 = 0; k0 < K1; k0 += 16) {
        #pragma unroll
        for (int i = 0; i < 4; ++i) {
            int e = tid + i * 256, r = e >> 4, kk = e & 15;
            int m = m0 + r, k = k0 + kk;
            As[r][kk] = (k < Ka) ? xa[m * lda_a + k] : xb[m * lda_b + (k - Ka)];
        }
        #pragma unroll
        for (int g = 0; g < 3; ++g)
            #pragma unroll
            for (int i = 0; i < 4; ++i) {
                int e = tid + i * 256, r = e >> 4, kk = e & 15;
                Ws[g][r][kk] = Wih[(size_t)(g * 256 + n0 + r) * ldw_i + k0 + kk];
            }
        __syncthreads();
        #pragma unroll
        for (int kk = 0; kk < 16; ++kk) {
            float a[4];
            #pragma unroll
            for (int i = 0; i < 4; ++i) a[i] = As[ty + 16 * i][kk];
            #pragma unroll
            for (int g = 0; g < 3; ++g) {
                float b[4];
                #pragma unroll
                for (int j = 0; j < 4; ++j) b[j] = Ws[g][tx + 16 * j][kk];
                #pragma unroll
                for (int i = 0; i < 4; ++i)
                    #pragma unroll
                    for (int j = 0; j < 4; ++j) acci[g][i][j] += a[i] * b[j];
            }
        }
        __syncthreads();
    }
    // sweep 2: gh = h @ Whh^T (K=256)
    for (int k0 = 0; k0 < 256; k0 += 16) {
        #pragma unroll
        for (int i = 0; i < 4; ++i) {
            int e = tid + i * 256, r = e >> 4, kk = e & 15;
            As[r][kk] = h[(size_t)(m0 + r) * 256 + k0 + kk];
        }
        #pragma unroll
        for (int g = 0; g < 3; ++g)
            #pragma unroll
            for (int i = 0; i < 4; ++i) {
                int e = tid + i * 256, r = e >> 4, kk = e & 15;
                Ws[g][r][kk] = Whh[(size_t)(g * 256 + n0 + r) * 256 + k0 + kk];
            }
        __syncthreads();
        #pragma unroll
        for (int kk = 0; kk < 16; ++kk) {
            float a[4];
            #pragma unroll
            for (int i = 0; i < 4; ++i) a[i] = As[ty + 16 * i][kk];
            #pragma unroll
            for (int g = 0; g < 3; ++g) {
                float b[4];
                #pragma unroll
                for (int j = 0; j < 4; ++j) b[j] = Ws[g][tx + 16 * j][kk];
                #pragma unroll
                for (int i = 0; i < 4; ++i)
                    #pragma unroll
                    for (int j = 0; j < 4; ++j) acch[g][i][j] += a[i] * b[j];
            }
        }
        __syncthreads();
    }
    // combine
    #pragma unroll
    for (int i = 0; i < 4; ++i) {
        int row = m0 + ty + 16 * i;
        #pragma unroll
        for (int j = 0; j < 4; ++j) {
            int col = n0 + tx + 16 * j;
            float ir  = acci[0][i][j] + bih[col];
            float iz  = acci[1][i][j] + bih[col + 256];
            float inn = acci[2][i][j] + bih[col + 512];
            float hr  = acch[0][i][j] + bhh[col];
            float hz  = acch[1][i][j] + bhh[col + 256];
            float hn  = acch[2][i][j] + bhh[col + 512];
            float r = sigmoidf_(ir + hr);
            float z = sigmoidf_(iz + hz);
            float n = tanhf(inn + r * hn);
            float hv = h[(size_t)row * 256 + col];
            float hp = (1.0f - z) * n + z * hv;
            h_out[(size_t)row * 256 + col] = hp;
            if (sum_out) sum_out[(size_t)row * 256 + col] = hp + add_in[(size_t)row * 256 + col];
        }
    }
}

// ---------------------------------------------------------------------------
// Per-batch Bahdanau attention: q = h @ Q^T; score = tanh(pm+q)@v (masked);
// softmax; att = align @ enc. One block per batch, 256 threads (4 waves).
// ---------------------------------------------------------------------------
__global__ __launch_bounds__(256)
void attn_kernel(const float* __restrict__ h,
                 const float* __restrict__ Q,
                 const float* __restrict__ pm,
                 const float* __restrict__ enc,
                 const float* __restrict__ vW,
                 const int* __restrict__ mlen,
                 float* __restrict__ att_out,
                 float* __restrict__ align_out, int t_step)
{
    __shared__ float hv[256], qv[256], vv[256], al[200];
    __shared__ float sc[200];
    const int b = blockIdx.x, tid = threadIdx.x;
    hv[tid] = h[(size_t)b * 256 + tid];
    vv[tid] = vW[tid];
    __syncthreads();
    // q_j = sum_k Q[j,k] * h[k]
    {
        float s = 0.0f;
        const float* qrow = Q + (size_t)tid * 256;
        for (int k = 0; k < 256; ++k) s += qrow[k] * hv[k];
        qv[tid] = s;
    }
    __syncthreads();
    const int wave = tid >> 6, lane = tid & 63;
    const int len = mlen[b];
    for (int i = wave; i < 200; i += 4) {
        const float* pr = pm + ((size_t)b * 200 + i) * 256;
        int d0 = lane * 4;
        float p = 0.0f;
        #pragma unroll
        for (int u = 0; u < 4; ++u) { int d = d0 + u; p += vv[d] * tanhf(pr[d] + qv[d]); }
        #pragma unroll
        for (int off = 32; off; off >>= 1) p += __shfl_down(p, off);
        if (lane == 0) sc[i] = (i < len) ? p : -1e9f;
    }
    __syncthreads();
    if (wave == 0) {
        float v0 = sc[lane], v1 = sc[lane + 64], v2 = sc[lane + 128];
        float v3 = (lane < 8) ? sc[lane + 192] : -1e30f;
        float mx = fmaxf(fmaxf(v0, v1), fmaxf(v2, v3));
        #pragma unroll
        for (int off = 32; off; off >>= 1) mx = fmaxf(mx, __shfl_xor(mx, off));
        float e0 = expf(v0 - mx), e1 = expf(v1 - mx), e2 = expf(v2 - mx);
        float e3 = (lane < 8) ? expf(v3 - mx) : 0.0f;
        float ss = e0 + e1 + e2 + e3;
        #pragma unroll
        for (int off = 32; off; off >>= 1) ss += __shfl_xor(ss, off);
        float inv = 1.0f / ss;
        float* ao = align_out + (size_t)b * 40000 + (size_t)t_step * 200;
        al[lane] = e0 * inv;        ao[lane] = e0 * inv;
        al[lane + 64] = e1 * inv;   ao[lane + 64] = e1 * inv;
        al[lane + 128] = e2 * inv;  ao[lane + 128] = e2 * inv;
        if (lane < 8) { al[lane + 192] = e3 * inv; ao[lane + 192] = e3 * inv; }
    }
    __syncthreads();
    // att_d = sum_t al[t] * enc[b,t,d]
    float a = 0.0f;
    const float* er = enc + (size_t)b * 200 * 256 + tid;
    for (int t2 = 0; t2 < 200; ++t2) a += al[t2] * er[(size_t)t2 * 256];
    att_out[(size_t)b * 256 + tid] = a;
}

// ---------------------------------------------------------------------------
extern "C" void kernel_launch(void* const* d_in, const int* in_sizes, int n_in,
                              void* d_out, int out_size, void* d_ws, size_t ws_size,
                              hipStream_t stream)
{
    const float* enc    = (const float*)d_in[0];
    const float* inputs = (const float*)d_in[1];
    const int*   mlen   = (const int*)d_in[2];
    const float* pW1 = (const float*)d_in[3];  const float* pb1 = (const float*)d_in[4];
    const float* pW2 = (const float*)d_in[5];  const float* pb2 = (const float*)d_in[6];
    const float* aWih = (const float*)d_in[7]; const float* abih = (const float*)d_in[8];
    const float* aWhh = (const float*)d_in[9]; const float* abhh = (const float*)d_in[10];
    const float* memW = (const float*)d_in[11];
    const float* qW   = (const float*)d_in[12];
    const float* vW   = (const float*)d_in[13];
    const float* pjW  = (const float*)d_in[14]; const float* pjb = (const float*)d_in[15];
    const float* w1ih = (const float*)d_in[16]; const float* w1bih = (const float*)d_in[17];
    const float* w1hh = (const float*)d_in[18]; const float* w1bhh = (const float*)d_in[19];
    const float* w2ih = (const float*)d_in[20]; const float* w2bih = (const float*)d_in[21];
    const float* w2hh = (const float*)d_in[22]; const float* w2bhh = (const float*)d_in[23];
    const float* melW = (const float*)d_in[24]; const float* melb = (const float*)d_in[25];

    float* out = (float*)d_out;
    float* ws  = (float*)d_ws;

    float* X1   = ws;                    // [51200,256]
    float* X2   = X1 + 13107200;         // [51200,128]  rows m = t*256+b
    float* pm   = X2 + 6553600;          // [256,200,256]
    float* dall = pm + 13107200;         // [200,256,256] rows m = t*256+b
    float* S    = dall + 13107200;       // states
    float* ha[2]  = { S,             S + 65536 };
    float* h1b[2] = { S + 2 * 65536, S + 3 * 65536 };
    float* h2b[2] = { S + 4 * 65536, S + 5 * 65536 };
    float* att = S + 6 * 65536;
    float* d0  = S + 7 * 65536;
    float* d1  = S + 8 * 65536;

    // zero initial states (h_a, h1, h2 ping-pong buffers + attention)
    hipMemsetAsync(S, 0, 7 * 65536 * sizeof(float), stream);

    // prenet1: X1 = relu(prev @ W1^T + b1), prev virtual (teacher forcing shift)
    gemm_kernel<2, 1><<<dim3(800, 4), 256, 0, stream>>>(
        inputs, 0, 400, nullptr, 0, 0, pW1, 400, pb1, X1, 256, 51200, 256);
    // prenet2: X2 = relu(X1 @ W2^T + b2)
    gemm_kernel<0, 1><<<dim3(800, 2), 256, 0, stream>>>(
        X1, 256, 256, nullptr, 0, 0, pW2, 256, pb2, X2, 128, 51200, 128);
    // processed_memory = enc @ mem_W^T
    gemm_kernel<0, 0><<<dim3(800, 4), 256, 0, stream>>>(
        enc, 256, 256, nullptr, 0, 0, memW, 256, nullptr, pm, 256, 51200, 256);

    for (int t = 0; t < 200; ++t) {
        const int pi = t & 1, po = pi ^ 1;
        // attention GRU: cell_in = [x2_t (128), attention (256)]
        gru_kernel<<<dim3(4, 4), 256, 0, stream>>>(
            X2 + (size_t)t * 32768, 128, 128, att, 256, 256, ha[pi],
            aWih, 384, abih, aWhh, abhh, ha[po], nullptr, nullptr);
        // Bahdanau attention (q, score, softmax, context); writes align to d_out
        attn_kernel<<<dim3(256), 256, 0, stream>>>(
            ha[po], qW, pm, enc, vW, mlen, att, out + ALIGN_OFF, t);
        // d0 = [attn_h, attention] @ proj_W^T + b
        gemm_kernel<1, 0><<<dim3(4, 4), 256, 0, stream>>>(
            ha[po], 256, 256, att, 256, 256, pjW, 512, pjb, d0, 256, 256, 256);
        // dec1: h1' = GRU(d0, h1); d1 = h1' + d0
        gru_kernel<<<dim3(4, 4), 256, 0, stream>>>(
            d0, 256, 256, nullptr, 0, 0, h1b[pi],
            w1ih, 256, w1bih, w1hh, w1bhh, h1b[po], d0, d1);
        // dec2: h2' = GRU(d1, h2); d2 = h2' + d1 -> dall[t]
        gru_kernel<<<dim3(4, 4), 256, 0, stream>>>(
            d1, 256, 256, nullptr, 0, 0, h2b[pi],
            w2ih, 256, w2bih, w2hh, w2bhh, h2b[po], d1, dall + (size_t)t * 65536);
    }

    // mel projection: out[b,t,:] = dall[t,b,:] @ mel_W^T + mel_b
    gemm_kernel<0, 2><<<dim3(800, 7), 256, 0, stream>>>(
        dall, 256, 256, nullptr, 0, 0, melW, 256, melb, out, 400, 51200, 400);
}

// Round 3
// 66091.010 us; speedup vs baseline: 1.2105x; 1.2105x over previous
//
#include <hip/hip_runtime.h>
#include <math.h>

// B=256, T_ENC=200, D=256, T_MEL=1000, NMEL=80, R=5, IN_R=400, Td=200
#define ALIGN_OFF 20480000   // 256*200*400

__device__ __forceinline__ float sigf(float x) {
    return __builtin_amdgcn_rcpf(1.0f + __expf(-x));
}
__device__ __forceinline__ float tanhff(float x) {
    float e = __expf(2.0f * x);
    return 1.0f - 2.0f * __builtin_amdgcn_rcpf(e + 1.0f);
}

// ---------------------------------------------------------------------------
// 128x128-tile fp32 GEMM, 8x8 per thread.
// C = act(A @ W^T + bias)
// AMODE: 0 plain A[m*lda+k]; 2 = teacher-forcing virtual A (prenet1):
//        row m -> t=m>>8,b=m&255; t==0 -> 0 else inputs[b*80000+(t-1)*400+k]
// EPI: 0 plain, 1 relu, 2 mel-layout store C[b*80000+t*400+col]
// ---------------------------------------------------------------------------
template<int AMODE, int EPI>
__global__ __launch_bounds__(256)
void gemm128(const float* __restrict__ A, int lda,
             const float* __restrict__ W, int ldw,
             const float* __restrict__ bias,
             float* __restrict__ C, int ldc, int M, int N, int K)
{
    __shared__ float As[16][128];
    __shared__ float Bs[16][128];
    const int m0 = blockIdx.x * 128, n0 = blockIdx.y * 128;
    const int tid = threadIdx.x;
    const int tx = tid & 15, ty = tid >> 4;
    float acc[8][8] = {};
    for (int k0 = 0; k0 < K; k0 += 16) {
        {
            const int m = tid >> 1, h = (tid & 1) * 8;
            const int grow = m0 + m;
            float4 a0, a1;
            if (AMODE == 2) {
                int t = grow >> 8, b = grow & 255;
                if (t == 0) { a0 = make_float4(0, 0, 0, 0); a1 = a0; }
                else {
                    const float* p = A + (size_t)b * 80000 + (t - 1) * 400 + k0 + h;
                    a0 = *(const float4*)p; a1 = *(const float4*)(p + 4);
                }
            } else {
                const float* p = A + (size_t)grow * lda + k0 + h;
                a0 = *(const float4*)p; a1 = *(const float4*)(p + 4);
            }
            As[h + 0][m] = a0.x; As[h + 1][m] = a0.y; As[h + 2][m] = a0.z; As[h + 3][m] = a0.w;
            As[h + 4][m] = a1.x; As[h + 5][m] = a1.y; As[h + 6][m] = a1.z; As[h + 7][m] = a1.w;
            const int gn = n0 + m;
            float4 b0, b1;
            if (gn < N) {
                const float* p = W + (size_t)gn * ldw + k0 + h;
                b0 = *(const float4*)p; b1 = *(const float4*)(p + 4);
            } else { b0 = make_float4(0, 0, 0, 0); b1 = b0; }
            Bs[h + 0][m] = b0.x; Bs[h + 1][m] = b0.y; Bs[h + 2][m] = b0.z; Bs[h + 3][m] = b0.w;
            Bs[h + 4][m] = b1.x; Bs[h + 5][m] = b1.y; Bs[h + 6][m] = b1.z; Bs[h + 7][m] = b1.w;
        }
        __syncthreads();
        #pragma unroll
        for (int kk = 0; kk < 16; ++kk) {
            float av[8], bv[8];
            *(float4*)&av[0] = *(const float4*)&As[kk][ty * 8];
            *(float4*)&av[4] = *(const float4*)&As[kk][ty * 8 + 4];
            *(float4*)&bv[0] = *(const float4*)&Bs[kk][tx * 8];
            *(float4*)&bv[4] = *(const float4*)&Bs[kk][tx * 8 + 4];
            #pragma unroll
            for (int i = 0; i < 8; ++i)
                #pragma unroll
                for (int j = 0; j < 8; ++j)
                    acc[i][j] += av[i] * bv[j];
        }
        __syncthreads();
    }
    #pragma unroll
    for (int i = 0; i < 8; ++i) {
        const int row = m0 + ty * 8 + i;
        const int t_ = row >> 8, b_ = row & 255;
        #pragma unroll
        for (int j4 = 0; j4 < 2; ++j4) {
            const int col = n0 + tx * 8 + j4 * 4;
            if (col >= N) continue;
            float4 v;
            float* pv = &v.x;
            #pragma unroll
            for (int u = 0; u < 4; ++u) {
                float x = acc[i][j4 * 4 + u] + (bias ? bias[col + u] : 0.0f);
                if (EPI == 1) x = fmaxf(x, 0.0f);
                pv[u] = x;
            }
            if (EPI == 2) *(float4*)(C + (size_t)b_ * 80000 + t_ * 400 + col) = v;
            else          *(float4*)(C + (size_t)row * ldc + col) = v;
        }
    }
}

// ---------------------------------------------------------------------------
// Grid barrier (all 256 blocks co-resident: 1 block/CU on 256 CUs).
// ---------------------------------------------------------------------------
__device__ __forceinline__ void gsync(unsigned* bar, unsigned nb)
{
    __syncthreads();
    if (threadIdx.x == 0) {
        __threadfence();
        unsigned gen = __hip_atomic_load(bar + 1, __ATOMIC_RELAXED, __HIP_MEMORY_SCOPE_AGENT);
        unsigned a = __hip_atomic_fetch_add(bar, 1u, __ATOMIC_ACQ_REL, __HIP_MEMORY_SCOPE_AGENT);
        if (a == nb - 1u) {
            __hip_atomic_store(bar, 0u, __ATOMIC_RELAXED, __HIP_MEMORY_SCOPE_AGENT);
            __hip_atomic_fetch_add(bar + 1, 1u, __ATOMIC_RELEASE, __HIP_MEMORY_SCOPE_AGENT);
        } else {
            while (__hip_atomic_load(bar + 1, __ATOMIC_ACQUIRE, __HIP_MEMORY_SCOPE_AGENT) == gen) {
                __builtin_amdgcn_s_sleep(1);
            }
        }
        __threadfence();
    }
    __syncthreads();
}

// ---------------------------------------------------------------------------
// Fused GRU phase: 256 blocks as 16 row-tiles x 16 col-tiles (16x16 each).
// NOTE: begins with __syncthreads() — the P5 -> next-step P1 transition has
// no grid barrier, so without it wave 0 overwrites smem that waves 1-3 are
// still reading (round-2 bug: absmax 1.28).
// ---------------------------------------------------------------------------
template<int KX, bool CONCAT>
__device__ __forceinline__ void gru_gate(
    float* smem, int bid, int tid,
    const float* __restrict__ xA, const float* __restrict__ xB,
    const float* __restrict__ hbuf,
    const float* __restrict__ Wih, const float* __restrict__ bih,
    const float* __restrict__ Whh, const float* __restrict__ bhh,
    float* __restrict__ hout, float* __restrict__ res1)
{
    __syncthreads();   // protect smem reuse across unbarriered phase boundary
    const int br = bid >> 4, bc = bid & 15;
    const int m0 = br * 16, n0 = bc * 16;
    constexpr int XW = KX / 4;
    float4* xs4 = (float4*)smem;          // [16][XW]
    float4* hs4 = xs4 + 16 * XW;          // [16][64]
    for (int idx = tid; idx < 16 * XW; idx += 256) {
        int r = idx / XW, kk = idx - r * XW;
        float4 v;
        if (CONCAT) {
            v = (kk < 32)
              ? *(const float4*)(xA + (size_t)(m0 + r) * 128 + kk * 4)
              : *(const float4*)(xB + (size_t)(m0 + r) * 256 + (kk - 32) * 4);
        } else {
            v = *(const float4*)(xA + (size_t)(m0 + r) * 256 + kk * 4);
        }
        xs4[idx] = v;
    }
    for (int idx = tid; idx < 1024; idx += 256) {
        hs4[idx] = *(const float4*)(hbuf + (size_t)(m0 + (idx >> 6)) * 256 + (idx & 63) * 4);
    }
    __syncthreads();
    const int tr = tid >> 4, tc = tid & 15;
    const int row = m0 + tr, col = n0 + tc;
    float ai0 = 0.f, ai1 = 0.f, ai2 = 0.f;
    {
        const float4* wr0 = (const float4*)(Wih + (size_t)(col) * KX);
        const float4* wr1 = (const float4*)(Wih + (size_t)(256 + col) * KX);
        const float4* wr2 = (const float4*)(Wih + (size_t)(512 + col) * KX);
        const float4* xr = xs4 + tr * XW;
        #pragma unroll 4
        for (int k = 0; k < XW; ++k) {
            float4 a = xr[k];
            float4 u0 = wr0[k], u1 = wr1[k], u2 = wr2[k];
            ai0 += a.x * u0.x + a.y * u0.y + a.z * u0.z + a.w * u0.w;
            ai1 += a.x * u1.x + a.y * u1.y + a.z * u1.z + a.w * u1.w;
            ai2 += a.x * u2.x + a.y * u2.y + a.z * u2.z + a.w * u2.w;
        }
    }
    float ah0 = 0.f, ah1 = 0.f, ah2 = 0.f;
    {
        const float4* wr0 = (const float4*)(Whh + (size_t)(col) * 256);
        const float4* wr1 = (const float4*)(Whh + (size_t)(256 + col) * 256);
        const float4* wr2 = (const float4*)(Whh + (size_t)(512 + col) * 256);
        const float4* hr = hs4 + tr * 64;
        #pragma unroll 4
        for (int k = 0; k < 64; ++k) {
            float4 a = hr[k];
            float4 u0 = wr0[k], u1 = wr1[k], u2 = wr2[k];
            ah0 += a.x * u0.x + a.y * u0.y + a.z * u0.z + a.w * u0.w;
            ah1 += a.x * u1.x + a.y * u1.y + a.z * u1.z + a.w * u1.w;
            ah2 += a.x * u2.x + a.y * u2.y + a.z * u2.z + a.w * u2.w;
        }
    }
    const float hold = ((const float*)hs4)[tr * 256 + col];
    const float ir = ai0 + bih[col], iz = ai1 + bih[col + 256], in_ = ai2 + bih[col + 512];
    const float hr_ = ah0 + bhh[col], hz = ah1 + bhh[col + 256], hn = ah2 + bhh[col + 512];
    const float r = sigf(ir + hr_);
    const float z = sigf(iz + hz);
    const float n = tanhff(in_ + r * hn);
    const float hp = (1.f - z) * n + z * hold;
    hout[(size_t)row * 256 + col] = hp;
    if (res1) {
        res1[(size_t)row * 256 + col] = hp + ((const float*)xs4)[tr * KX + col];
    }
}

// ---------------------------------------------------------------------------
// Persistent decoder loop: 256 blocks x 256 threads, 4 grid barriers / step.
// ---------------------------------------------------------------------------
__global__ __launch_bounds__(256)
void decoder_loop(
    const float* __restrict__ X2,    // [200][256][128]
    const float* __restrict__ pm,    // [256][200][256]
    const float* __restrict__ enc,   // [256][200][256]
    const int*   __restrict__ mlen,
    const float* __restrict__ aWih, const float* __restrict__ abih,
    const float* __restrict__ aWhh, const float* __restrict__ abhh,
    const float* __restrict__ qW,   const float* __restrict__ vW,
    const float* __restrict__ pjW,  const float* __restrict__ pjb,
    const float* __restrict__ w1ih, const float* __restrict__ w1bih,
    const float* __restrict__ w1hh, const float* __restrict__ w1bhh,
    const float* __restrict__ w2ih, const float* __restrict__ w2bih,
    const float* __restrict__ w2hh, const float* __restrict__ w2bhh,
    float* __restrict__ ha,   float* __restrict__ h1g, float* __restrict__ h2g,
    float* __restrict__ attb, float* __restrict__ d0g, float* __restrict__ d1g,
    float* __restrict__ dall, float* __restrict__ alout,
    unsigned* __restrict__ bar)
{
    __shared__ float smem[10240];
    const int bid = blockIdx.x, tid = threadIdx.x;

    for (int t = 0; t < 200; ++t) {
        const int pi = t & 1, po = pi ^ 1;
        const float* attP = attb + pi * 65536;
        float* attN = attb + po * 65536;
        const float* hnew = ha + po * 65536;

        // ---- P1: attention GRU: h_a' = GRU([x2_t | att], h_a) ----
        gru_gate<384, true>(smem, bid, tid,
            X2 + (size_t)t * 32768, attP, ha + pi * 65536,
            aWih, abih, aWhh, abhh, ha + po * 65536, nullptr);
        gsync(bar, 256);

        // ---- P2: Bahdanau attention (block = batch) ----
        {
            float* hv = smem;        // 256
            float* qv = smem + 256;  // 256
            float* vv = smem + 512;  // 256
            float* sc = smem + 768;  // 200
            float* al = smem + 1024; // 200
            const int b = bid;
            hv[tid] = hnew[(size_t)b * 256 + tid];
            vv[tid] = vW[tid];
            __syncthreads();
            {
                const float4* qr = (const float4*)(qW + (size_t)tid * 256);
                const float4* h4 = (const float4*)hv;
                float s = 0.f;
                #pragma unroll 8
                for (int k = 0; k < 64; ++k) {
                    float4 q = qr[k], h = h4[k];
                    s += q.x * h.x + q.y * h.y + q.z * h.z + q.w * h.w;
                }
                qv[tid] = s;
            }
            __syncthreads();
            const int wave = tid >> 6, lane = tid & 63;
            const int len = mlen[b];
            for (int i = wave; i < 200; i += 4) {
                const float4 pr = *(const float4*)(pm + ((size_t)b * 200 + i) * 256 + lane * 4);
                const int d = lane * 4;
                float p = vv[d]     * tanhff(pr.x + qv[d])
                        + vv[d + 1] * tanhff(pr.y + qv[d + 1])
                        + vv[d + 2] * tanhff(pr.z + qv[d + 2])
                        + vv[d + 3] * tanhff(pr.w + qv[d + 3]);
                #pragma unroll
                for (int off = 32; off; off >>= 1) p += __shfl_down(p, off);
                if (lane == 0) sc[i] = (i < len) ? p : -1e9f;
            }
            __syncthreads();
            if (wave == 0) {
                float v0 = sc[lane], v1 = sc[lane + 64], v2 = sc[lane + 128];
                float v3 = (lane < 8) ? sc[lane + 192] : -1e30f;
                float mx = fmaxf(fmaxf(v0, v1), fmaxf(v2, v3));
                #pragma unroll
                for (int off = 32; off; off >>= 1) mx = fmaxf(mx, __shfl_xor(mx, off));
                float e0 = __expf(v0 - mx), e1 = __expf(v1 - mx), e2 = __expf(v2 - mx);
                float e3 = (lane < 8) ? __expf(v3 - mx) : 0.f;
                float ss = e0 + e1 + e2 + e3;
                #pragma unroll
                for (int off = 32; off; off >>= 1) ss += __shfl_xor(ss, off);
                float inv = 1.0f / ss;
                float* ao = alout + (size_t)b * 40000 + (size_t)t * 200;
                al[lane]       = e0 * inv; ao[lane]       = e0 * inv;
                al[lane + 64]  = e1 * inv; ao[lane + 64]  = e1 * inv;
                al[lane + 128] = e2 * inv; ao[lane + 128] = e2 * inv;
                if (lane < 8) { al[lane + 192] = e3 * inv; ao[lane + 192] = e3 * inv; }
            }
            __syncthreads();
            {
                float a = 0.f;
                const float* er = enc + (size_t)b * 51200 + tid;
                #pragma unroll 4
                for (int i2 = 0; i2 < 200; ++i2) a += al[i2] * er[(size_t)i2 * 256];
                attN[(size_t)b * 256 + tid] = a;
            }
        }
        gsync(bar, 256);

        // ---- P3: d0 = [h_a' | att'] @ pjW^T + pjb ----
        {
            const int br = bid >> 4, bc = bid & 15;
            const int m0 = br * 16, n0 = bc * 16;
            float4* xs4 = (float4*)smem;  // [16][128]
            for (int idx = tid; idx < 2048; idx += 256) {
                int r = idx >> 7, kk = idx & 127;
                float4 v = (kk < 64)
                    ? *(const float4*)(hnew + (size_t)(m0 + r) * 256 + kk * 4)
                    : *(const float4*)(attN + (size_t)(m0 + r) * 256 + (kk - 64) * 4);
                xs4[idx] = v;
            }
            __syncthreads();
            const int tr = tid >> 4, tc = tid & 15;
            const int row = m0 + tr, col = n0 + tc;
            const float4* wr = (const float4*)(pjW + (size_t)col * 512);
            const float4* xr = xs4 + tr * 128;
            float s = 0.f;
            #pragma unroll 8
            for (int k = 0; k < 128; ++k) {
                float4 w = wr[k], x = xr[k];
                s += w.x * x.x + w.y * x.y + w.z * x.z + w.w * x.w;
            }
            d0g[(size_t)row * 256 + col] = s + pjb[col];
        }
        gsync(bar, 256);

        // ---- P4: dec1 GRU + residual: d1 = h1' + d0 ----
        gru_gate<256, false>(smem, bid, tid,
            d0g, nullptr, h1g + pi * 65536,
            w1ih, w1bih, w1hh, w1bhh, h1g + po * 65536, d1g);
        gsync(bar, 256);

        // ---- P5: dec2 GRU + residual -> dall[t] ----
        gru_gate<256, false>(smem, bid, tid,
            d1g, nullptr, h2g + pi * 65536,
            w2ih, w2bih, w2hh, w2bhh, h2g + po * 65536,
            dall + (size_t)t * 65536);
        // no grid barrier needed: global consumers are >=4 barriers away;
        // block-local smem hazard handled by __syncthreads at gru_gate entry
    }
}

// ---------------------------------------------------------------------------
extern "C" void kernel_launch(void* const* d_in, const int* in_sizes, int n_in,
                              void* d_out, int out_size, void* d_ws, size_t ws_size,
                              hipStream_t stream)
{
    const float* enc    = (const float*)d_in[0];
    const float* inputs = (const float*)d_in[1];
    const int*   mlen   = (const int*)d_in[2];
    const float* pW1 = (const float*)d_in[3];  const float* pb1 = (const float*)d_in[4];
    const float* pW2 = (const float*)d_in[5];  const float* pb2 = (const float*)d_in[6];
    const float* aWih = (const float*)d_in[7]; const float* abih = (const float*)d_in[8];
    const float* aWhh = (const float*)d_in[9]; const float* abhh = (const float*)d_in[10];
    const float* memW = (const float*)d_in[11];
    const float* qW   = (const float*)d_in[12];
    const float* vW   = (const float*)d_in[13];
    const float* pjW  = (const float*)d_in[14]; const float* pjb = (const float*)d_in[15];
    const float* w1ih = (const float*)d_in[16]; const float* w1bih = (const float*)d_in[17];
    const float* w1hh = (const float*)d_in[18]; const float* w1bhh = (const float*)d_in[19];
    const float* w2ih = (const float*)d_in[20]; const float* w2bih = (const float*)d_in[21];
    const float* w2hh = (const float*)d_in[22]; const float* w2bhh = (const float*)d_in[23];
    const float* melW = (const float*)d_in[24]; const float* melb = (const float*)d_in[25];

    float* out = (float*)d_out;
    float* ws  = (float*)d_ws;

    // workspace layout (floats)
    float* X2 = ws;                       // 200*256*128 = 6,553,600
    float* S  = X2 + 6553600;             // 10 x 65536 states
    float* ha   = S;
    float* h1g  = S + 2 * 65536;
    float* h2g  = S + 4 * 65536;
    float* attb = S + 6 * 65536;
    float* d0g  = S + 8 * 65536;
    float* d1g  = S + 9 * 65536;
    unsigned* bar = (unsigned*)(S + 655360);   // 16 floats reserved
    float* X1 = S + 655360 + 16;          // 13,107,200 (aliased as dall)
    float* pmw = X1 + 13107200;           // 13,107,200
    float* dall = X1;

    // zero states + barrier
    hipMemsetAsync(S, 0, (655360 + 16) * sizeof(float), stream);

    // prenet1: X1 = relu(prev @ W1^T + b1)  [51200,256], virtual shifted input
    gemm128<2, 1><<<dim3(400, 2), 256, 0, stream>>>(
        inputs, 0, pW1, 400, pb1, X1, 256, 51200, 256, 400);
    // prenet2: X2 = relu(X1 @ W2^T + b2)  [51200,128]
    gemm128<0, 1><<<dim3(400, 1), 256, 0, stream>>>(
        X1, 256, pW2, 256, pb2, X2, 128, 51200, 128, 256);
    // processed_memory = enc @ memW^T  [51200,256]
    gemm128<0, 0><<<dim3(400, 2), 256, 0, stream>>>(
        enc, 256, memW, 256, nullptr, pmw, 256, 51200, 256, 256);

    // the 200-step sequential decoder
    decoder_loop<<<256, 256, 0, stream>>>(
        X2, pmw, enc, mlen,
        aWih, abih, aWhh, abhh, qW, vW, pjW, pjb,
        w1ih, w1bih, w1hh, w1bhh, w2ih, w2bih, w2hh, w2bhh,
        ha, h1g, h2g, attb, d0g, d1g, dall, out + ALIGN_OFF, bar);

    // mel projection: out[b,t,:] = dall[t,b,:] @ melW^T + melb
    gemm128<0, 2><<<dim3(400, 4), 256, 0, stream>>>(
        dall, 256, melW, 256, melb, out, 400, 51200, 400, 256);
}

// Round 4
// 55568.262 us; speedup vs baseline: 1.4398x; 1.1894x over previous
//
#include <hip/hip_runtime.h>
#include <math.h>

// B=256, T_ENC=200, D=256, T_MEL=1000, NMEL=80, R=5, IN_R=400, Td=200
#define ALIGN_OFF 20480000   // 256*200*400

__device__ __forceinline__ float sigf(float x) {
    return __builtin_amdgcn_rcpf(1.0f + __expf(-x));
}
__device__ __forceinline__ float tanhff(float x) {
    float e = __expf(2.0f * x);
    return 1.0f - 2.0f * __builtin_amdgcn_rcpf(e + 1.0f);
}

// ---------------------------------------------------------------------------
// 128x128-tile fp32 GEMM (prenet / processed_memory / mel) — unchanged.
// ---------------------------------------------------------------------------
template<int AMODE, int EPI>
__global__ __launch_bounds__(256)
void gemm128(const float* __restrict__ A, int lda,
             const float* __restrict__ W, int ldw,
             const float* __restrict__ bias,
             float* __restrict__ C, int ldc, int M, int N, int K)
{
    __shared__ float As[16][128];
    __shared__ float Bs[16][128];
    const int m0 = blockIdx.x * 128, n0 = blockIdx.y * 128;
    const int tid = threadIdx.x;
    const int tx = tid & 15, ty = tid >> 4;
    float acc[8][8] = {};
    for (int k0 = 0; k0 < K; k0 += 16) {
        {
            const int m = tid >> 1, h = (tid & 1) * 8;
            const int grow = m0 + m;
            float4 a0, a1;
            if (AMODE == 2) {
                int t = grow >> 8, b = grow & 255;
                if (t == 0) { a0 = make_float4(0, 0, 0, 0); a1 = a0; }
                else {
                    const float* p = A + (size_t)b * 80000 + (t - 1) * 400 + k0 + h;
                    a0 = *(const float4*)p; a1 = *(const float4*)(p + 4);
                }
            } else {
                const float* p = A + (size_t)grow * lda + k0 + h;
                a0 = *(const float4*)p; a1 = *(const float4*)(p + 4);
            }
            As[h + 0][m] = a0.x; As[h + 1][m] = a0.y; As[h + 2][m] = a0.z; As[h + 3][m] = a0.w;
            As[h + 4][m] = a1.x; As[h + 5][m] = a1.y; As[h + 6][m] = a1.z; As[h + 7][m] = a1.w;
            const int gn = n0 + m;
            float4 b0, b1;
            if (gn < N) {
                const float* p = W + (size_t)gn * ldw + k0 + h;
                b0 = *(const float4*)p; b1 = *(const float4*)(p + 4);
            } else { b0 = make_float4(0, 0, 0, 0); b1 = b0; }
            Bs[h + 0][m] = b0.x; Bs[h + 1][m] = b0.y; Bs[h + 2][m] = b0.z; Bs[h + 3][m] = b0.w;
            Bs[h + 4][m] = b1.x; Bs[h + 5][m] = b1.y; Bs[h + 6][m] = b1.z; Bs[h + 7][m] = b1.w;
        }
        __syncthreads();
        #pragma unroll
        for (int kk = 0; kk < 16; ++kk) {
            float av[8], bv[8];
            *(float4*)&av[0] = *(const float4*)&As[kk][ty * 8];
            *(float4*)&av[4] = *(const float4*)&As[kk][ty * 8 + 4];
            *(float4*)&bv[0] = *(const float4*)&Bs[kk][tx * 8];
            *(float4*)&bv[4] = *(const float4*)&Bs[kk][tx * 8 + 4];
            #pragma unroll
            for (int i = 0; i < 8; ++i)
                #pragma unroll
                for (int j = 0; j < 8; ++j)
                    acc[i][j] += av[i] * bv[j];
        }
        __syncthreads();
    }
    #pragma unroll
    for (int i = 0; i < 8; ++i) {
        const int row = m0 + ty * 8 + i;
        const int t_ = row >> 8, b_ = row & 255;
        #pragma unroll
        for (int j4 = 0; j4 < 2; ++j4) {
            const int col = n0 + tx * 8 + j4 * 4;
            if (col >= N) continue;
            float4 v;
            float* pv = &v.x;
            #pragma unroll
            for (int u = 0; u < 4; ++u) {
                float x = acc[i][j4 * 4 + u] + (bias ? bias[col + u] : 0.0f);
                if (EPI == 1) x = fmaxf(x, 0.0f);
                pv[u] = x;
            }
            if (EPI == 2) *(float4*)(C + (size_t)b_ * 80000 + t_ * 400 + col) = v;
            else          *(float4*)(C + (size_t)row * ldc + col) = v;
        }
    }
}

// ---------------------------------------------------------------------------
// Pack W [N][K] row-major -> P [K/4][N] float4 (k4-packed). One-time, tiny.
// Consecutive threads write consecutive float4 (coalesced stores).
// ---------------------------------------------------------------------------
__global__ __launch_bounds__(256)
void pack_w(const float* __restrict__ W, float4* __restrict__ P, int N, int K)
{
    const int tot = N * (K >> 2);
    for (int i = blockIdx.x * 256 + threadIdx.x; i < tot; i += gridDim.x * 256) {
        const int n = i % N, k4 = i / N;
        P[(size_t)k4 * N + n] = *(const float4*)(W + (size_t)n * K + (k4 << 2));
    }
}

// ---------------------------------------------------------------------------
// Grid barrier (256 blocks, all co-resident).
// ---------------------------------------------------------------------------
__device__ __forceinline__ void gsync(unsigned* bar, unsigned nb)
{
    __syncthreads();
    if (threadIdx.x == 0) {
        __threadfence();
        unsigned gen = __hip_atomic_load(bar + 1, __ATOMIC_RELAXED, __HIP_MEMORY_SCOPE_AGENT);
        unsigned a = __hip_atomic_fetch_add(bar, 1u, __ATOMIC_ACQ_REL, __HIP_MEMORY_SCOPE_AGENT);
        if (a == nb - 1u) {
            __hip_atomic_store(bar, 0u, __ATOMIC_RELAXED, __HIP_MEMORY_SCOPE_AGENT);
            __hip_atomic_fetch_add(bar + 1, 1u, __ATOMIC_RELEASE, __HIP_MEMORY_SCOPE_AGENT);
        } else {
            while (__hip_atomic_load(bar + 1, __ATOMIC_ACQUIRE, __HIP_MEMORY_SCOPE_AGENT) == gen) {
                __builtin_amdgcn_s_sleep(1);
            }
        }
        __threadfence();
    }
    __syncthreads();
}

// ---------------------------------------------------------------------------
// GRU phase, 768 threads, block tile = 4 rows x 64 cols, one gate per thread.
// Weights are k4-packed: W*P[k4][768] float4; lanes read 64 consecutive
// float4 (1KB/wave-instr, coalesced); activations broadcast from LDS.
// Entry __syncthreads protects smem across the unbarriered P5->P1 boundary.
// ---------------------------------------------------------------------------
template<int KX, bool CONCAT>
__device__ __forceinline__ void gru2(
    float* smem, int bid, int tid,
    const float* __restrict__ xA, const float* __restrict__ xB,
    const float* __restrict__ hbuf,
    const float4* __restrict__ WihP, const float* __restrict__ bih,
    const float4* __restrict__ WhhP, const float* __restrict__ bhh,
    float* __restrict__ hout, float* __restrict__ res1)
{
    __syncthreads();
    const int br = bid >> 2, bc = bid & 3;
    const int r0 = br * 4, c0 = bc * 64;
    constexpr int XW = KX / 4;            // 96 (KX=384) or 64 (KX=256)
    float4* xs = (float4*)smem;           // [4][XW]
    float4* hs = xs + 4 * XW;             // [4][64]
    float*  pi_ = (float*)(hs + 256);     // [3][256]
    float*  ph_ = pi_ + 768;              // [3][256]
    for (int i = tid; i < 4 * XW; i += 768) {
        const int r = i / XW, k = i % XW;
        float4 v;
        if (CONCAT) {
            v = (k < 32) ? *(const float4*)(xA + (size_t)(r0 + r) * 128 + k * 4)
                         : *(const float4*)(xB + (size_t)(r0 + r) * 256 + (k - 32) * 4);
        } else {
            v = *(const float4*)(xA + (size_t)(r0 + r) * 256 + k * 4);
        }
        xs[i] = v;
    }
    if (tid < 256) {
        hs[tid] = *(const float4*)(hbuf + (size_t)(r0 + (tid >> 6)) * 256 + (tid & 63) * 4);
    }
    __syncthreads();
    {
        const int g = tid >> 8, idx = tid & 255;
        const int r4 = idx >> 6, cl = idx & 63;
        const int n = (g << 8) + c0 + cl;
        float ai = 0.f, ah = 0.f;
        const float4* xr = xs + r4 * XW;
        const float4* wp = WihP + n;
        #pragma unroll 8
        for (int k = 0; k < XW; ++k) {
            const float4 a = xr[k];
            const float4 w = wp[(size_t)k * 768];
            ai += a.x * w.x + a.y * w.y + a.z * w.z + a.w * w.w;
        }
        const float4* hr = hs + r4 * 64;
        const float4* wq = WhhP + n;
        #pragma unroll 8
        for (int k = 0; k < 64; ++k) {
            const float4 a = hr[k];
            const float4 w = wq[(size_t)k * 768];
            ah += a.x * w.x + a.y * w.y + a.z * w.z + a.w * w.w;
        }
        pi_[(g << 8) + idx] = ai + bih[n];
        ph_[(g << 8) + idx] = ah + bhh[n];
    }
    __syncthreads();
    if (tid < 256) {
        const int r4 = tid >> 6, cl = tid & 63;
        const int col = c0 + cl, row = r0 + r4;
        const float vr = sigf(pi_[tid] + ph_[tid]);
        const float vz = sigf(pi_[256 + tid] + ph_[256 + tid]);
        const float vn = tanhff(pi_[512 + tid] + vr * ph_[512 + tid]);
        const float hold = ((const float*)hs)[r4 * 256 + col];
        const float hp = (1.f - vz) * vn + vz * hold;
        hout[(size_t)row * 256 + col] = hp;
        if (res1) res1[(size_t)row * 256 + col] = hp + ((const float*)xs)[r4 * KX + col];
    }
}

// ---------------------------------------------------------------------------
// Persistent decoder loop: 256 blocks x 768 threads, 4 grid barriers / step.
// ---------------------------------------------------------------------------
__global__ __launch_bounds__(768)
void decoder_loop(
    const float* __restrict__ X2,    // [200][256][128]
    const float* __restrict__ pm,    // [256][200][256]
    const float* __restrict__ enc,   // [256][200][256]
    const int*   __restrict__ mlen,
    const float4* __restrict__ aWihP, const float* __restrict__ abih,
    const float4* __restrict__ aWhhP, const float* __restrict__ abhh,
    const float4* __restrict__ qWP,   const float* __restrict__ vW,
    const float4* __restrict__ pjWP,  const float* __restrict__ pjb,
    const float4* __restrict__ w1ihP, const float* __restrict__ w1bih,
    const float4* __restrict__ w1hhP, const float* __restrict__ w1bhh,
    const float4* __restrict__ w2ihP, const float* __restrict__ w2bih,
    const float4* __restrict__ w2hhP, const float* __restrict__ w2bhh,
    float* __restrict__ ha,   float* __restrict__ h1g, float* __restrict__ h2g,
    float* __restrict__ attb, float* __restrict__ d0g, float* __restrict__ d1g,
    float* __restrict__ dall, float* __restrict__ alout,
    unsigned* __restrict__ bar)
{
    __shared__ float smem[4608];
    const int bid = blockIdx.x, tid = threadIdx.x;
    const int br = bid >> 2, bc = bid & 3;
    const int r0 = br * 4, c0 = bc * 64;

    for (int t = 0; t < 200; ++t) {
        const int pi = t & 1, po = pi ^ 1;
        const float* attP = attb + pi * 65536;
        float* attN = attb + po * 65536;
        const float* hnew = ha + po * 65536;

        // ---- P1: attention GRU: h_a' = GRU([x2_t | att], h_a) ----
        gru2<384, true>(smem, bid, tid,
            X2 + (size_t)t * 32768, attP, ha + pi * 65536,
            aWihP, abih, aWhhP, abhh, ha + po * 65536, nullptr);
        gsync(bar, 256);

        // ---- P2: Bahdanau attention (block = batch) ----
        {
            float* hv = smem;          // 256
            float* qv = hv + 256;      // 256
            float* vv = qv + 256;      // 256
            float* sc = vv + 256;      // 204
            float* al = sc + 204;      // 204
            float* part = al + 204;    // 768
            const int b = bid;
            if (tid < 256) hv[tid] = hnew[(size_t)b * 256 + tid];
            else if (tid < 512) vv[tid - 256] = vW[tid - 256];
            __syncthreads();
            if (tid < 256) {
                const float4* h4 = (const float4*)hv;
                const float4* qp = qWP + tid;
                float s = 0.f;
                #pragma unroll 8
                for (int k = 0; k < 64; ++k) {
                    const float4 a = h4[k];
                    const float4 w = qp[(size_t)k * 256];
                    s += a.x * w.x + a.y * w.y + a.z * w.z + a.w * w.w;
                }
                qv[tid] = s;
            }
            __syncthreads();
            const int wv = tid >> 6, ln = tid & 63;
            const int len = mlen[b];
            for (int i = wv; i < 200; i += 12) {
                const float4 pr = *(const float4*)(pm + ((size_t)b * 200 + i) * 256 + ln * 4);
                const float4 q4 = ((const float4*)qv)[ln];
                const float4 v4 = ((const float4*)vv)[ln];
                float p = v4.x * tanhff(pr.x + q4.x)
                        + v4.y * tanhff(pr.y + q4.y)
                        + v4.z * tanhff(pr.z + q4.z)
                        + v4.w * tanhff(pr.w + q4.w);
                #pragma unroll
                for (int off = 32; off; off >>= 1) p += __shfl_down(p, off);
                if (ln == 0) sc[i] = (i < len) ? p : -1e9f;
            }
            __syncthreads();
            if (wv == 0) {
                float v0 = sc[ln], v1 = sc[ln + 64], v2 = sc[ln + 128];
                float v3 = (ln < 8) ? sc[ln + 192] : -1e30f;
                float mx = fmaxf(fmaxf(v0, v1), fmaxf(v2, v3));
                #pragma unroll
                for (int off = 32; off; off >>= 1) mx = fmaxf(mx, __shfl_xor(mx, off));
                float e0 = __expf(v0 - mx), e1 = __expf(v1 - mx), e2 = __expf(v2 - mx);
                float e3 = (ln < 8) ? __expf(v3 - mx) : 0.f;
                float ss = e0 + e1 + e2 + e3;
                #pragma unroll
                for (int off = 32; off; off >>= 1) ss += __shfl_xor(ss, off);
                float inv = 1.0f / ss;
                float* ao = alout + (size_t)b * 40000 + (size_t)t * 200;
                al[ln]       = e0 * inv; ao[ln]       = e0 * inv;
                al[ln + 64]  = e1 * inv; ao[ln + 64]  = e1 * inv;
                al[ln + 128] = e2 * inv; ao[ln + 128] = e2 * inv;
                if (ln < 8) { al[ln + 192] = e3 * inv; ao[ln + 192] = e3 * inv; }
            }
            __syncthreads();
            {
                const int seg = tid >> 8, d = tid & 255;
                const int t0 = seg * 67, t1 = (seg == 2) ? 200 : t0 + 67;
                float a = 0.f;
                const float* er = enc + (size_t)b * 51200 + d;
                for (int tt = t0; tt < t1; ++tt) a += al[tt] * er[(size_t)tt * 256];
                part[seg * 256 + d] = a;
            }
            __syncthreads();
            if (tid < 256) {
                attN[(size_t)b * 256 + tid] = part[tid] + part[256 + tid] + part[512 + tid];
            }
        }
        gsync(bar, 256);

        // ---- P3: d0 = [h_a' | att'] @ pjW^T + pjb (split-K by 2) ----
        {
            float4* xs = (float4*)smem;            // [4][128]
            float* part = (float*)(xs + 512);      // [2][256]
            for (int i = tid; i < 512; i += 768) {
                const int r = i >> 7, k = i & 127;
                const float4 v = (k < 64)
                    ? *(const float4*)(hnew + (size_t)(r0 + r) * 256 + k * 4)
                    : *(const float4*)(attN + (size_t)(r0 + r) * 256 + (k - 64) * 4);
                xs[i] = v;
            }
            __syncthreads();
            if (tid < 512) {
                const int half = tid >> 8, idx = tid & 255;
                const int r4 = idx >> 6, cl = idx & 63;
                const float4* xr = xs + r4 * 128 + half * 64;
                const float4* wp = pjWP + (size_t)half * 64 * 256 + c0 + cl;
                float s = 0.f;
                #pragma unroll 8
                for (int k = 0; k < 64; ++k) {
                    const float4 a = xr[k];
                    const float4 w = wp[(size_t)k * 256];
                    s += a.x * w.x + a.y * w.y + a.z * w.z + a.w * w.w;
                }
                part[(half << 8) + idx] = s;
            }
            __syncthreads();
            if (tid < 256) {
                const int r4 = tid >> 6, cl = tid & 63;
                d0g[(size_t)(r0 + r4) * 256 + c0 + cl] =
                    part[tid] + part[256 + tid] + pjb[c0 + cl];
            }
        }
        gsync(bar, 256);

        // ---- P4: dec1 GRU + residual: d1 = h1' + d0 ----
        gru2<256, false>(smem, bid, tid,
            d0g, nullptr, h1g + pi * 65536,
            w1ihP, w1bih, w1hhP, w1bhh, h1g + po * 65536, d1g);
        gsync(bar, 256);

        // ---- P5: dec2 GRU + residual -> dall[t] ----
        gru2<256, false>(smem, bid, tid,
            d1g, nullptr, h2g + pi * 65536,
            w2ihP, w2bih, w2hhP, w2bhh, h2g + po * 65536,
            dall + (size_t)t * 65536);
        // no grid barrier: consumers are >=4 barriers away; smem hazard
        // handled by __syncthreads at gru2 entry
    }
}

// ---------------------------------------------------------------------------
extern "C" void kernel_launch(void* const* d_in, const int* in_sizes, int n_in,
                              void* d_out, int out_size, void* d_ws, size_t ws_size,
                              hipStream_t stream)
{
    const float* enc    = (const float*)d_in[0];
    const float* inputs = (const float*)d_in[1];
    const int*   mlen   = (const int*)d_in[2];
    const float* pW1 = (const float*)d_in[3];  const float* pb1 = (const float*)d_in[4];
    const float* pW2 = (const float*)d_in[5];  const float* pb2 = (const float*)d_in[6];
    const float* aWih = (const float*)d_in[7]; const float* abih = (const float*)d_in[8];
    const float* aWhh = (const float*)d_in[9]; const float* abhh = (const float*)d_in[10];
    const float* memW = (const float*)d_in[11];
    const float* qW   = (const float*)d_in[12];
    const float* vW   = (const float*)d_in[13];
    const float* pjW  = (const float*)d_in[14]; const float* pjb = (const float*)d_in[15];
    const float* w1ih = (const float*)d_in[16]; const float* w1bih = (const float*)d_in[17];
    const float* w1hh = (const float*)d_in[18]; const float* w1bhh = (const float*)d_in[19];
    const float* w2ih = (const float*)d_in[20]; const float* w2bih = (const float*)d_in[21];
    const float* w2hh = (const float*)d_in[22]; const float* w2bhh = (const float*)d_in[23];
    const float* melW = (const float*)d_in[24]; const float* melb = (const float*)d_in[25];

    float* out = (float*)d_out;
    float* ws  = (float*)d_ws;

    // workspace layout (floats)
    float* X2 = ws;                       // 200*256*128 = 6,553,600
    float* S  = X2 + 6553600;             // 10 x 65536 states
    float* ha   = S;
    float* h1g  = S + 2 * 65536;
    float* h2g  = S + 4 * 65536;
    float* attb = S + 6 * 65536;
    float* d0g  = S + 8 * 65536;
    float* d1g  = S + 9 * 65536;
    unsigned* bar = (unsigned*)(S + 655360);   // 16 floats reserved
    float* X1 = S + 655360 + 16;          // 13,107,200 (aliased as dall)
    float* pmw = X1 + 13107200;           // 13,107,200
    float* dall = X1;
    // packed weights after pmw
    float* pk = pmw + 13107200;
    float4* aWihP = (float4*)pk;              // 96*768  = 73728 f4
    float4* aWhhP = aWihP + 73728;            // 64*768  = 49152
    float4* w1ihP = aWhhP + 49152;            // 49152
    float4* w1hhP = w1ihP + 49152;            // 49152
    float4* w2ihP = w1hhP + 49152;            // 49152
    float4* w2hhP = w2ihP + 49152;            // 49152
    float4* pjWP  = w2hhP + 49152;            // 128*256 = 32768
    float4* qWP   = pjWP + 32768;             // 64*256  = 16384

    // zero initial states + barrier
    hipMemsetAsync(S, 0, (655360 + 16) * sizeof(float), stream);

    // pack weights into [K/4][N] float4 layout (one-time, tiny)
    pack_w<<<64, 256, 0, stream>>>(aWih, aWihP, 768, 384);
    pack_w<<<64, 256, 0, stream>>>(aWhh, aWhhP, 768, 256);
    pack_w<<<64, 256, 0, stream>>>(w1ih, w1ihP, 768, 256);
    pack_w<<<64, 256, 0, stream>>>(w1hh, w1hhP, 768, 256);
    pack_w<<<64, 256, 0, stream>>>(w2ih, w2ihP, 768, 256);
    pack_w<<<64, 256, 0, stream>>>(w2hh, w2hhP, 768, 256);
    pack_w<<<64, 256, 0, stream>>>(pjW,  pjWP,  256, 512);
    pack_w<<<64, 256, 0, stream>>>(qW,   qWP,   256, 256);

    // prenet1: X1 = relu(prev @ W1^T + b1)  [51200,256]
    gemm128<2, 1><<<dim3(400, 2), 256, 0, stream>>>(
        inputs, 0, pW1, 400, pb1, X1, 256, 51200, 256, 400);
    // prenet2: X2 = relu(X1 @ W2^T + b2)  [51200,128]
    gemm128<0, 1><<<dim3(400, 1), 256, 0, stream>>>(
        X1, 256, pW2, 256, pb2, X2, 128, 51200, 128, 256);
    // processed_memory = enc @ memW^T  [51200,256]
    gemm128<0, 0><<<dim3(400, 2), 256, 0, stream>>>(
        enc, 256, memW, 256, nullptr, pmw, 256, 51200, 256, 256);

    // the 200-step sequential decoder
    decoder_loop<<<256, 768, 0, stream>>>(
        X2, pmw, enc, mlen,
        aWihP, abih, aWhhP, abhh, qWP, vW, pjWP, pjb,
        w1ihP, w1bih, w1hhP, w1bhh, w2ihP, w2bih, w2hhP, w2bhh,
        ha, h1g, h2g, attb, d0g, d1g, dall, out + ALIGN_OFF, bar);

    // mel projection: out[b,t,:] = dall[t,b,:] @ melW^T + melb
    gemm128<0, 2><<<dim3(400, 4), 256, 0, stream>>>(
        dall, 256, melW, 256, melb, out, 400, 51200, 400, 256);
}